// Round 7
// baseline (349.984 us; speedup 1.0000x reference)
//
#include <hip/hip_runtime.h>

// Problem constants (from reference)
#define NC 32768
#define ND 1024
#define NQ 256    // float4 chunks per row (ND/4)
#define NB 16384
#define KEEP 0.95f
#define OMK  0.05f   // 1 - keep
#define KCAP 16      // per-class sample-list cap; P(Poisson(0.5) >= 17) ~ 1e-19
#define RPB 4        // rows per tile in loss kernel
#define BLOCKS 1024  // 4 blocks/CU, fully resident
#define TPB (NC / RPB / BLOCKS)  // 8 tiles per block

typedef float f4 __attribute__((ext_vector_type(4)));

__device__ __forceinline__ void fma4(f4& a, float w, f4 b) {
    a.x = fmaf(w, b.x, a.x);
    a.y = fmaf(w, b.y, a.y);
    a.z = fmaf(w, b.z, a.z);
    a.w = fmaf(w, b.w, a.w);
}

// Kernel 1: count occurrences per class, scatter sample indices into
// per-class lists (order arbitrary; the index itself encodes batch order).
__global__ void count_scatter_kernel(const int* __restrict__ the_class,
                                     int* __restrict__ counts,
                                     int* __restrict__ idx_list) {
    int i = blockIdx.x * blockDim.x + threadIdx.x;
    if (i < NB) {
        int c = the_class[i];
        int pos = atomicAdd(&counts[c], 1);
        if (pos < KCAP) idx_list[c * KCAP + pos] = i;
    }
}

// Kernel 2: per-class EMA metadata. One thread per class:
// decay[c] = keep^cnt; elist[c][j] = {sample_idx, (1-keep)*keep^{#later occ}}
__global__ void wprep_kernel(const int* __restrict__ counts,
                             const int* __restrict__ idx_list,
                             float* __restrict__ decays,
                             int2* __restrict__ elist) {
    int c = blockIdx.x * blockDim.x + threadIdx.x;
    int cnt = counts[c];
    float base = KEEP, r = 1.0f;
    for (int e = cnt; e > 0; e >>= 1) { if (e & 1) r *= base; base *= base; }
    decays[c] = r;
    int m = cnt < KCAP ? cnt : KCAP;
    int idx[KCAP];
    #pragma unroll
    for (int j = 0; j < KCAP; ++j)
        idx[j] = (j < m) ? idx_list[c * KCAP + j] : -1;  // sentinel never "later"
    #pragma unroll
    for (int j = 0; j < KCAP; ++j) {
        if (j < m) {
            int later = 0;
            #pragma unroll
            for (int l = 0; l < KCAP; ++l) later += (idx[l] > idx[j]);
            float w = OMK;
            for (int k = 0; k < later; ++k) w *= KEEP;
            int2 e; e.x = idx[j]; e.y = __float_as_int(w);
            elist[c * KCAP + j] = e;
        }
    }
}

// Kernel 3: fused EMA + L1 loss, persistent grid-stride with register
// double-buffering. Each block owns TPB*RPB consecutive rows; per tile:
//   (1) issue cur-tile gathers + t-loads   (oldest->newest ordering keeps
//   (2) issue NEXT-tile s-loads             partial vmcnt waits possible)
//   (3) compute cur tile (next-tile loads stay in flight)
// Metadata (counts/decays/elist) is block-uniform -> SGPR s_loads, which
// use lgkmcnt and never force vmcnt drains.
// Round-3/4 lesson: no launch_bounds min-waves (compiler restructures);
// round-4 replay evidence: kernel is latency-bound (same dur warm-L3 as
// cold), so the lever is SUSTAINED bytes-in-flight per wave.
__global__ __launch_bounds__(256) void loss_kernel(
    const float* __restrict__ s_logits,
    const float* __restrict__ t_logits,
    const float* __restrict__ logits,
    const int*   __restrict__ counts,
    const float* __restrict__ decays,
    const int2*  __restrict__ elist,
    float* __restrict__ out) {

    const int q = threadIdx.x;              // 0..255 float4 column
    const f4* s4 = (const f4*)s_logits;
    const f4* t4 = (const f4*)t_logits;
    const f4* l4 = (const f4*)logits;

    f4 svA[RPB], svB[RPB], tv[RPB], lv[RPB];
    float decA[RPB], decB[RPB];
    int   mA[RPB],  mB[RPB];
    int2  eA[RPB],  eB[RPB];

    const int base0 = blockIdx.x * (TPB * RPB);
    float lsum = 0.0f;

#define LOAD_META(DEC, M, E, base)                                  \
    _Pragma("unroll")                                               \
    for (int r = 0; r < RPB; ++r) {                                 \
        DEC[r] = decays[(base) + r];                                \
        int cnt = counts[(base) + r];                               \
        M[r] = cnt < KCAP ? cnt : KCAP;                             \
        E[r] = elist[((base) + r) * KCAP];                          \
    }

#define LOAD_SV(SV, base)                                           \
    _Pragma("unroll")                                               \
    for (int r = 0; r < RPB; ++r)                                   \
        SV[r] = s4[(size_t)((base) + r) * NQ + q];

#define ISSUE_CUR(M, E, base)                                       \
    _Pragma("unroll")                                               \
    for (int r = 0; r < RPB; ++r)                                   \
        if (M[r] > 0) lv[r] = l4[(size_t)E[r].x * NQ + q];          \
    _Pragma("unroll")                                               \
    for (int r = 0; r < RPB; ++r)                                   \
        tv[r] = t4[(size_t)((base) + r) * NQ + q];

#define COMPUTE(SV, DEC, M, E, base)                                \
    _Pragma("unroll")                                               \
    for (int r = 0; r < RPB; ++r) {                                 \
        f4 acc;                                                     \
        acc.x = SV[r].x * DEC[r];                                   \
        acc.y = SV[r].y * DEC[r];                                   \
        acc.z = SV[r].z * DEC[r];                                   \
        acc.w = SV[r].w * DEC[r];                                   \
        if (M[r] > 0) {                                             \
            fma4(acc, __int_as_float(E[r].y), lv[r]);               \
            for (int j = 1; j < M[r]; ++j) {  /* rare: P ~ 9% */    \
                int2 e = elist[((base) + r) * KCAP + j];            \
                f4 g = l4[(size_t)e.x * NQ + q];                    \
                fma4(acc, __int_as_float(e.y), g);                  \
            }                                                       \
        }                                                           \
        lsum += fabsf(acc.x - tv[r].x) + fabsf(acc.y - tv[r].y) +   \
                fabsf(acc.z - tv[r].z) + fabsf(acc.w - tv[r].w);    \
    }

    // prologue: tile 0 into buffer A
    LOAD_META(decA, mA, eA, base0);
    LOAD_SV(svA, base0);

    #pragma unroll
    for (int i = 0; i < TPB; ++i) {
        const int cc = base0 + i * RPB;
        if ((i & 1) == 0) {
            ISSUE_CUR(mA, eA, cc);
            if (i < TPB - 1) {
                LOAD_META(decB, mB, eB, cc + RPB);
                LOAD_SV(svB, cc + RPB);
            }
            COMPUTE(svA, decA, mA, eA, cc);
        } else {
            ISSUE_CUR(mB, eB, cc);
            if (i < TPB - 1) {
                LOAD_META(decA, mA, eA, cc + RPB);
                LOAD_SV(svA, cc + RPB);
            }
            COMPUTE(svB, decB, mB, eB, cc);
        }
    }

#undef LOAD_META
#undef LOAD_SV
#undef ISSUE_CUR
#undef COMPUTE

    // wave reduction (64 lanes) then cross-wave via LDS
    #pragma unroll
    for (int off = 32; off > 0; off >>= 1) lsum += __shfl_down(lsum, off);
    __shared__ float wsum[4];
    const int wave = threadIdx.x >> 6, lane = threadIdx.x & 63;
    if (lane == 0) wsum[wave] = lsum;
    __syncthreads();
    if (threadIdx.x == 0) {
        float total = (wsum[0] + wsum[1] + wsum[2] + wsum[3]) * (1.0f / NC);
        atomicAdd(out, total);
    }
}

extern "C" void kernel_launch(void* const* d_in, const int* in_sizes, int n_in,
                              void* d_out, int out_size, void* d_ws, size_t ws_size,
                              hipStream_t stream) {
    const float* s_logits  = (const float*)d_in[0];
    const float* t_logits  = (const float*)d_in[1];
    const float* logits    = (const float*)d_in[2];
    const int*   the_class = (const int*)d_in[3];
    float* out = (float*)d_out;

    // workspace layout (8B-aligned segments)
    int*   counts   = (int*)d_ws;                      // NC ints   (128 KB)
    int*   idx_list = counts + NC;                     // NC*KCAP   (2 MB)
    float* decays   = (float*)(idx_list + NC * KCAP);  // NC floats (128 KB)
    int2*  elist    = (int2*)(decays + NC);            // NC*KCAP int2 (4 MB)

    hipMemsetAsync(counts, 0, NC * sizeof(int), stream);
    hipMemsetAsync(d_out, 0, sizeof(float), stream);

    count_scatter_kernel<<<NB / 256, 256, 0, stream>>>(the_class, counts, idx_list);
    wprep_kernel<<<NC / 256, 256, 0, stream>>>(counts, idx_list, decays, elist);
    loss_kernel<<<BLOCKS, 256, 0, stream>>>(s_logits, t_logits, logits,
                                            counts, decays, elist, out);
}